// Round 12
// baseline (742.305 us; speedup 1.0000x reference)
//
#include <hip/hip_runtime.h>

#define T_LEN 128
#define NB_BINS 15
#define TSLAB 32
#define NPASS 4

// ---------------------------------------------------------------------------
// Pass kernel. Block = 1024 threads = 16 waves; each half-wave (32 lanes)
// owns ONE sequence for this pass (32 seqs/block, 1024 blocks).
//  - L chunk (32 steps x 128B = 4KB/seq) loaded in 8 back-to-back dwordx4
//    instructions (two dense 512B segments per instr) -> DRAM-row bursts.
//  - dots: lane k holds quad (k&7) of row i*4+((k&31)>>3); 8-lane shfl reduce.
//  - (a,c,y,m) assembled per step in LDS; 32-step scan done redundantly by
//    all 32 lanes of the half (lane kk keeps step kk) -> 128B dense writes.
//  - carry (zm,zv) per seq in global ws between passes (pass p reads p-1's).
//  - ll: block-reduced, one atomicAdd per block per pass.
// ---------------------------------------------------------------------------
__global__ __launch_bounds__(1024) void k_pass(
    const float*  __restrict__ S,
    const float*  __restrict__ Y,
    const float*  __restrict__ Mm,
    const float4* __restrict__ L4,
    const float4* __restrict__ C4,
    const float4* __restrict__ wgs4,
    const float4* __restrict__ wbs4,
    const float4* __restrict__ wgd4,
    const float4* __restrict__ wbd4,
    const float*  __restrict__ p_psi,
    const float*  __restrict__ p_gA,
    const float*  __restrict__ p_lsz,
    const float*  __restrict__ p_b0,
    const float*  __restrict__ p_bZ,
    const float*  __restrict__ p_bbins,
    const float*  __restrict__ p_bT,
    float2* __restrict__ carry,
    float*  __restrict__ zf,
    float*  __restrict__ zvo,
    float*  __restrict__ ll_out,
    int pass)
{
    __shared__ float  ldsG[16][2][TSLAB];
    __shared__ float  ldsB[16][2][TSLAB];
    __shared__ float4 tile[16][2][TSLAB];
    __shared__ float  ldsLL[16];
    __shared__ float  sbins[NB_BINS];

    const int tid  = threadIdx.x;
    if (tid < NB_BINS) sbins[tid] = p_bbins[tid];

    const int w    = tid >> 6;        // wave 0..15
    const int k    = tid & 63;        // lane
    const int half = k >> 5;          // 0/1: which seq of the wave
    const int kk   = k & 31;          // step-lane within half

    const int n = blockIdx.x * 32 + w * 2 + half;   // sequence

    // ---- burst: entire 4KB L chunk, 8 back-to-back dwordx4 ----
    const size_t cb = (size_t)n * (T_LEN * 8) + (size_t)pass * (TSLAB * 8);
    float4 Lb0 = L4[cb + 0*32 + kk], Lb1 = L4[cb + 1*32 + kk];
    float4 Lb2 = L4[cb + 2*32 + kk], Lb3 = L4[cb + 3*32 + kk];
    float4 Lb4 = L4[cb + 4*32 + kk], Lb5 = L4[cb + 5*32 + kk];
    float4 Lb6 = L4[cb + 6*32 + kk], Lb7 = L4[cb + 7*32 + kk];

    // ---- side loads: this lane's step ----
    const int sb  = n * T_LEN + pass * TSLAB;
    const float s_v = S[sb + kk];
    const float y_v = Y[sb + kk];
    const float m_v = Mm[sb + kk];

    // ---- scalar params ----
    const float psi  = p_psi[0];
    const float gA   = p_gA[0];
    const float e    = __expf(p_lsz[0]);
    const float sig2 = e * e;
    const float b0   = p_b0[0];
    const float bZ   = p_bZ[0];
    const float bT30 = p_bT[0] * (1.0f / 30.0f);
    const float psi2 = psi * psi;
    const float bZ2  = bZ * bZ;

    // ---- static dots (4-lane groups within the half) ----
    float gs, bs;
    {
        const int q = k & 3;
        const float4 c  = C4[n * 4 + q];
        const float4 wgq = wgs4[q];
        const float4 wbq = wbs4[q];
        gs = c.x*wgq.x + c.y*wgq.y + c.z*wgq.z + c.w*wgq.w;
        bs = c.x*wbq.x + c.y*wbq.y + c.z*wbq.z + c.w*wbq.w;
        gs += __shfl_xor(gs, 1, 64); gs += __shfl_xor(gs, 2, 64);
        bs += __shfl_xor(bs, 1, 64); bs += __shfl_xor(bs, 2, 64);
    }

    // ---- dynamic dots: 8-lane groups; write per-row g,b to LDS ----
    {
        const float4 wgq = wgd4[k & 7];
        const float4 wbq = wbd4[k & 7];
#define DOT(i, Lb) do {                                                       \
        float g = Lb.x*wgq.x + Lb.y*wgq.y + Lb.z*wgq.z + Lb.w*wgq.w;          \
        float b = Lb.x*wbq.x + Lb.y*wbq.y + Lb.z*wbq.z + Lb.w*wbq.w;          \
        g += __shfl_xor(g, 1, 64); g += __shfl_xor(g, 2, 64);                 \
        g += __shfl_xor(g, 4, 64);                                            \
        b += __shfl_xor(b, 1, 64); b += __shfl_xor(b, 2, 64);                 \
        b += __shfl_xor(b, 4, 64);                                            \
        if ((k & 7) == 0) {                                                   \
            const int t = (i) * 4 + (kk >> 3);                                \
            ldsG[w][half][t] = g; ldsB[w][half][t] = b;                       \
        }                                                                     \
    } while (0)
        DOT(0, Lb0); DOT(1, Lb1); DOT(2, Lb2); DOT(3, Lb3);
        DOT(4, Lb4); DOT(5, Lb5); DOT(6, Lb6); DOT(7, Lb7);
#undef DOT
    }
    __syncthreads();

    // ---- assemble (a,c,y,m) for this lane's step ----
    {
        int cnt = (int)fmaxf(0.0f, fminf(14.0f,
                      ceilf(fmaf(s_v, 3.0f, 7.5f)) - 1.0f));
        const float a = gA * s_v + ldsG[w][half][kk] + gs;
        const float c = b0 + sbins[cnt] + ldsB[w][half][kk] + bs
                      + bT30 * (float)(pass * TSLAB + kk);
        tile[w][half][kk] = make_float4(a, c, y_v, m_v);
    }
    __syncthreads();

    // ---- 32-step scan (redundant across the half's 32 lanes) ----
    float zm, zvv;
    if (pass == 0) { zm = 0.0f; zvv = 1.0f; }
    else           { const float2 c2 = carry[n]; zm = c2.x; zvv = c2.y; }

    float ll = 0.0f, pmk = 0.0f, pvk = 0.0f;
    #pragma unroll
    for (int t = 0; t < TSLAB; ++t) {
        const float4 pk = tile[w][half][t];
        const float zpm = fmaf(psi, zm, pk.x);
        const float zpv = fmaf(psi2, zvv, sig2);
        float logit = fmaf(bZ, zpm, pk.y);
        logit = fminf(fmaxf(logit, -20.0f), 20.0f);
        const float prob = __builtin_amdgcn_rcpf(1.0f + __expf(-logit));
        const float grad = (pk.z - prob) * bZ * pk.w;
        const float hess = fmaf(bZ2 * prob * (1.0f - prob), pk.w, 1e-6f);
        const float pvv  = __builtin_amdgcn_rcpf(
                             __builtin_amdgcn_rcpf(zpv + 1e-8f) + hess);
        const float pmm  = fmaf(pvv, grad, zpm);
        ll += (pk.z * __logf(prob + 1e-10f)
             + (1.0f - pk.z) * __logf(1.0f - prob + 1e-10f)) * pk.w;
        zm = pmm; zvv = pvv;
        if (t == kk) { pmk = pmm; pvk = pvv; }
    }

    // ---- carry out, dense outputs ----
    if (kk == 0) carry[n] = make_float2(zm, zvv);
    zf [sb + kk] = pmk;
    zvo[sb + kk] = pvk;

    // ---- ll: halves summed, block-reduced, one atomic per block ----
    float llw = ll + __shfl_xor(ll, 32, 64);
    if (k == 0) ldsLL[w] = llw;
    __syncthreads();
    if (tid == 0) {
        float t = 0.0f;
        #pragma unroll
        for (int i = 0; i < 16; ++i) t += ldsLL[i];
        atomicAdd(ll_out, t);
    }
}

// ---------------------------------------------------------------------------
extern "C" void kernel_launch(void* const* d_in, const int* in_sizes, int n_in,
                              void* d_out, int out_size, void* d_ws, size_t ws_size,
                              hipStream_t stream) {
    const float* S     = (const float*)d_in[0];
    const float* L     = (const float*)d_in[1];
    const float* C     = (const float*)d_in[2];
    const float* Y     = (const float*)d_in[3];
    const float* M     = (const float*)d_in[4];
    const float* psi   = (const float*)d_in[5];
    const float* gA    = (const float*)d_in[6];
    const float* wgd   = (const float*)d_in[7];
    const float* wgs   = (const float*)d_in[8];
    const float* lsz   = (const float*)d_in[9];
    const float* b0    = (const float*)d_in[10];
    const float* bZ    = (const float*)d_in[11];
    const float* bbins = (const float*)d_in[12];
    const float* wbd   = (const float*)d_in[13];
    const float* wbs   = (const float*)d_in[14];
    const float* bT    = (const float*)d_in[15];

    const int NT    = in_sizes[0];        // N*T = 4194304
    const int n_seq = NT / T_LEN;         // 32768

    float* zf = (float*)d_out;
    float* zv = zf + NT;
    float* ll = zf + 2 * (size_t)NT;

    float2* carry = (float2*)d_ws;        // 256KB carry between passes

    hipMemsetAsync((void*)ll, 0, sizeof(float), stream);

    const int blocks = n_seq / 32;        // 1024 blocks of 1024 threads
    for (int p = 0; p < NPASS; ++p) {
        k_pass<<<blocks, 1024, 0, stream>>>(
            S, Y, M,
            reinterpret_cast<const float4*>(L),
            reinterpret_cast<const float4*>(C),
            reinterpret_cast<const float4*>(wgs),
            reinterpret_cast<const float4*>(wbs),
            reinterpret_cast<const float4*>(wgd),
            reinterpret_cast<const float4*>(wbd),
            psi, gA, lsz, b0, bZ, bbins, bT,
            carry, zf, zv, ll, p);
    }
}

// Round 13
// 169.360 us; speedup vs baseline: 4.3830x; 4.3830x over previous
//
#include <hip/hip_runtime.h>

#define T_LEN 128
#define NB_BINS 15

// ---------------------------------------------------------------------------
// Fused kernel, 8 lanes per sequence (16 waves/CU), depth-2 chunk prefetch
// (3 rotating register buffers, counted vmcnt waits -> never drains),
// full-64B-line nontemporal output writes. Best measured: 168.5us total
// (~161.5us kernel), ~3.7 TB/s read -> at the platform read-path roofline.
// ---------------------------------------------------------------------------
__global__ __launch_bounds__(256, 4) void k_fused8(
    const float4* __restrict__ S4,
    const float4* __restrict__ Y4,
    const float4* __restrict__ M4,
    const float4* __restrict__ C4,
    const float4* __restrict__ L4,
    const float4* __restrict__ wgd4,
    const float4* __restrict__ wbd4,
    const float4* __restrict__ wgs4,
    const float4* __restrict__ wbs4,
    const float*  __restrict__ p_psi,
    const float*  __restrict__ p_gA,
    const float*  __restrict__ p_lsz,
    const float*  __restrict__ p_b0,
    const float*  __restrict__ p_bZ,
    const float*  __restrict__ p_bbins,
    const float*  __restrict__ p_bT,
    float* __restrict__ zf,
    float* __restrict__ zv,
    float*  __restrict__ ll_out)
{
    __shared__ float sbins[NB_BINS];
    if (threadIdx.x < NB_BINS) sbins[threadIdx.x] = p_bbins[threadIdx.x];
    __syncthreads();

    const int gtid = blockIdx.x * blockDim.x + threadIdx.x;
    const int n = gtid >> 3;     // sequence index
    const int j = gtid & 7;      // sublane within 8-lane group

    // lane j owns L row elements [4j, 4j+4)
    const float4 wg = wgd4[j];
    const float4 wb = wbd4[j];

    const float psi  = p_psi[0];
    const float gA   = p_gA[0];
    const float e    = __expf(p_lsz[0]);
    const float sig2 = e * e;
    const float b0   = p_b0[0];
    const float bZ   = p_bZ[0];
    const float bT30 = p_bT[0] * (1.0f / 30.0f);
    const float psi2 = psi * psi;
    const float bZ2  = bZ * bZ;

    // static dots: lanes j and j+4 duplicate element-quad j&3; xor 1,2 reduce
    float gs, bs;
    {
        const float4 c  = C4[n * 4 + (j & 3)];
        const float4 wgsv = wgs4[j & 3];
        const float4 wbsv = wbs4[j & 3];
        gs = c.x * wgsv.x + c.y * wgsv.y + c.z * wgsv.z + c.w * wgsv.w;
        bs = c.x * wbsv.x + c.y * wbsv.y + c.z * wbsv.z + c.w * wbsv.w;
        gs += __shfl_xor(gs, 1, 64); gs += __shfl_xor(gs, 2, 64);
        bs += __shfl_xor(bs, 1, 64); bs += __shfl_xor(bs, 2, 64);
    }

    const size_t lb = (size_t)n * 1024;   // L float4 base (16KB/seq)
    const int    sb = n * 32;             // S/Y/M float4 chunk base

    float zm = 0.0f, zvv = 1.0f, ll = 0.0f;
    float pmS0 = 0.f, pmS1 = 0.f, pvS0 = 0.f, pvS1 = 0.f;

#define LOAD(P, c) do {                                                       \
        const size_t rb = lb + (size_t)(c) * 32 + j;                          \
        P##0 = L4[rb];      P##1 = L4[rb + 8];                                \
        P##2 = L4[rb + 16]; P##3 = L4[rb + 24];                               \
        P##s = S4[sb + (c)]; P##y = Y4[sb + (c)]; P##m = M4[sb + (c)];        \
    } while (0)

#define STEP(i, Lv, SS, YY, MM, c) do {                                       \
        const float s_v = (SS), y_v = (YY), m_v = (MM);                       \
        float g   = Lv.x*wg.x + Lv.y*wg.y + Lv.z*wg.z + Lv.w*wg.w;            \
        float bdv = Lv.x*wb.x + Lv.y*wb.y + Lv.z*wb.z + Lv.w*wb.w;            \
        g   += __shfl_xor(g,   1, 64); g   += __shfl_xor(g,   2, 64);         \
        g   += __shfl_xor(g,   4, 64);                                        \
        bdv += __shfl_xor(bdv, 1, 64); bdv += __shfl_xor(bdv, 2, 64);         \
        bdv += __shfl_xor(bdv, 4, 64);                                        \
        int cnt = (int)fmaxf(0.0f, fminf(14.0f,                               \
                      ceilf(fmaf(s_v, 3.0f, 7.5f)) - 1.0f));                  \
        const float be   = sbins[cnt];                                        \
        const float zpm  = psi * zm + gA * s_v + g + gs;                      \
        const float zpv  = psi2 * zvv + sig2;                                 \
        float logit = b0 + bZ * zpm + be + bdv + bs                           \
                    + bT30 * (float)(4 * (c) + (i));                          \
        logit = fminf(fmaxf(logit, -20.0f), 20.0f);                           \
        const float prob = __builtin_amdgcn_rcpf(1.0f + __expf(-logit));      \
        const float grad = (y_v - prob) * bZ * m_v;                           \
        const float hess = bZ2 * prob * (1.0f - prob) * m_v + 1e-6f;          \
        const float pvv  = __builtin_amdgcn_rcpf(                             \
                   __builtin_amdgcn_rcpf(zpv + 1e-8f) + hess);                \
        const float pmm  = zpm + pvv * grad;                                  \
        zm = pmm; zvv = pvv;                                                  \
        /* lane owner = ((c&3)<<1) + (i>>1) stashes slot i&1 and adds ll */   \
        if (j == (((c) & 3) * 2 + ((i) >> 1))) {                              \
            if ((i) & 1) { pmS1 = pmm; pvS1 = pvv; }                          \
            else         { pmS0 = pmm; pvS0 = pvv; }                          \
            ll += (y_v * __logf(prob + 1e-10f)                                \
                 + (1.0f - y_v) * __logf(1.0f - prob + 1e-10f)) * m_v;        \
        }                                                                     \
    } while (0)

#define COMP(P, c) do {                                                       \
        STEP(0, P##0, P##s.x, P##y.x, P##m.x, c);                             \
        STEP(1, P##1, P##s.y, P##y.y, P##m.y, c);                             \
        STEP(2, P##2, P##s.z, P##y.z, P##m.z, c);                             \
        STEP(3, P##3, P##s.w, P##y.w, P##m.w, c);                             \
        if (((c) & 3) == 3) {  /* quad complete: 64B-line group write */      \
            const size_t ob = (size_t)n * 128 + ((c) >> 2) * 16 + j * 2;      \
            __builtin_nontemporal_store(pmS0, &zf[ob]);                       \
            __builtin_nontemporal_store(pmS1, &zf[ob + 1]);                   \
            __builtin_nontemporal_store(pvS0, &zv[ob]);                       \
            __builtin_nontemporal_store(pvS1, &zv[ob + 1]);                   \
        }                                                                     \
    } while (0)

    float4 A0, A1, A2, A3, As, Ay, Am;
    float4 B0, B1, B2, B3, Bs, By, Bm;
    float4 D0, D1, D2, D3, Ds, Dy, Dm;

    LOAD(A, 0);
    LOAD(B, 1);

    // 32 chunks; rotate A,B,D with depth-2 prefetch (loads never exceed 31)
    for (int k = 0; k < 30; k += 3) {
        LOAD(D, k + 2); COMP(A, k);
        LOAD(A, k + 3); COMP(B, k + 1);
        LOAD(B, k + 4); COMP(D, k + 2);
    }
    COMP(A, 30);
    COMP(B, 31);

#undef COMP
#undef STEP
#undef LOAD

    // each (seq, step) ll term counted exactly once -> full-wave reduce
    #pragma unroll
    for (int off = 1; off < 64; off <<= 1) ll += __shfl_xor(ll, off, 64);
    if ((threadIdx.x & 63) == 0) atomicAdd(ll_out, ll);
}

// ---------------------------------------------------------------------------
extern "C" void kernel_launch(void* const* d_in, const int* in_sizes, int n_in,
                              void* d_out, int out_size, void* d_ws, size_t ws_size,
                              hipStream_t stream) {
    const float* S     = (const float*)d_in[0];
    const float* L     = (const float*)d_in[1];
    const float* C     = (const float*)d_in[2];
    const float* Y     = (const float*)d_in[3];
    const float* M     = (const float*)d_in[4];
    const float* psi   = (const float*)d_in[5];
    const float* gA    = (const float*)d_in[6];
    const float* wgd   = (const float*)d_in[7];
    const float* wgs   = (const float*)d_in[8];
    const float* lsz   = (const float*)d_in[9];
    const float* b0    = (const float*)d_in[10];
    const float* bZ    = (const float*)d_in[11];
    const float* bbins = (const float*)d_in[12];
    const float* wbd   = (const float*)d_in[13];
    const float* wbs   = (const float*)d_in[14];
    const float* bT    = (const float*)d_in[15];

    const int NT    = in_sizes[0];        // N*T = 4194304
    const int n_seq = NT / T_LEN;         // 32768

    float* zf = (float*)d_out;
    float* zv = zf + NT;
    float* ll = zf + 2 * (size_t)NT;

    hipMemsetAsync((void*)ll, 0, sizeof(float), stream);

    const int threads = 256;
    const int blocks  = (n_seq * 8) / threads;   // 1024 blocks, 4096 waves
    k_fused8<<<blocks, threads, 0, stream>>>(
        reinterpret_cast<const float4*>(S),
        reinterpret_cast<const float4*>(Y),
        reinterpret_cast<const float4*>(M),
        reinterpret_cast<const float4*>(C),
        reinterpret_cast<const float4*>(L),
        reinterpret_cast<const float4*>(wgd),
        reinterpret_cast<const float4*>(wbd),
        reinterpret_cast<const float4*>(wgs),
        reinterpret_cast<const float4*>(wbs),
        psi, gA, lsz, b0, bZ, bbins, bT,
        zf, zv, ll);
}